// Round 1
// baseline (246.373 us; speedup 1.0000x reference)
//
#include <hip/hip_runtime.h>

#define NB 2
#define NS 128
#define ND 128
#define NF 512
#define NV 1024
#define NH 4
#define NDK 32
#define NL 2

// f(v) = rint(m*2^3) * 2^(2e-3)  with v = m*2^e, 0.5<=|m|<1
// Equivalent to the reference's l_mul per-term value (exponent alignment by
// `me` is an exact power-of-2 rescale => numerically a no-op).
__device__ __forceinline__ float lmul_tf(float v) {
    int e;
    float m = frexpf(v, &e);
    return ldexpf(rintf(m * 8.0f), 2 * e - 3);
}

// Transform all weights into contiguous ws: [Wq|Wk|Wv|Wo|W1|W2|Wout]
// sizes: 4*32768 + 131072 + 131072 + 131072 = 524288
__global__ __launch_bounds__(256) void k_transform_all(
    const float* __restrict__ Wq, const float* __restrict__ Wk,
    const float* __restrict__ Wv, const float* __restrict__ Wo,
    const float* __restrict__ W1, const float* __restrict__ W2,
    const float* __restrict__ Wout, float* __restrict__ dst)
{
    int i = blockIdx.x * 256 + threadIdx.x;
    const float* src; int off;
    if (i < 131072) {
        src = (i < 65536) ? ((i < 32768) ? Wq : Wk) : ((i < 98304) ? Wv : Wo);
        off = i & 32767;
    } else if (i < 262144) { src = W1;   off = i - 131072; }
    else if (i < 393216)  { src = W2;   off = i - 262144; }
    else                  { src = Wout; off = i - 393216; }
    dst[i] = lmul_tf(src[off]);
}

__global__ __launch_bounds__(256) void k_embed(
    const int* __restrict__ tok, const float* __restrict__ emb,
    const float* __restrict__ pos, float* __restrict__ x)
{
    int i = blockIdx.x * 256 + threadIdx.x;   // over NB*NS*ND = 32768
    int d  = i & (ND - 1);
    int bs = i >> 7;
    int s  = bs & (NS - 1);
    x[i] = emb[tok[bs] * ND + d] + pos[s * ND + d];
}

// out[M,N] = f(X)[M,K] * Wf[N,K]^T + bias, optional relu.
// 32x32 tile, 256 threads, 2x2 micro-tile per thread. X transformed on load.
__global__ __launch_bounds__(256) void k_lmul_mm(
    const float* __restrict__ X, const float* __restrict__ Wf,
    const float* __restrict__ bias, float* __restrict__ out,
    int N, int K, int relu)
{
    __shared__ float Xs[32][33];
    __shared__ float Ws[32][33];
    int t  = threadIdx.x;
    int m0 = blockIdx.y * 32, n0 = blockIdx.x * 32;
    int tm = t >> 4, tn = t & 15;
    int lr = t >> 3, lc = (t & 7) * 4;
    float acc00 = 0.f, acc01 = 0.f, acc10 = 0.f, acc11 = 0.f;
    for (int k0 = 0; k0 < K; k0 += 32) {
        float4 xv = *(const float4*)(X + (size_t)(m0 + lr) * K + k0 + lc);
        Xs[lr][lc + 0] = lmul_tf(xv.x);
        Xs[lr][lc + 1] = lmul_tf(xv.y);
        Xs[lr][lc + 2] = lmul_tf(xv.z);
        Xs[lr][lc + 3] = lmul_tf(xv.w);
        float4 wv = *(const float4*)(Wf + (size_t)(n0 + lr) * K + k0 + lc);
        Ws[lr][lc + 0] = wv.x;
        Ws[lr][lc + 1] = wv.y;
        Ws[lr][lc + 2] = wv.z;
        Ws[lr][lc + 3] = wv.w;
        __syncthreads();
        #pragma unroll
        for (int kk = 0; kk < 32; ++kk) {
            float a0 = Xs[tm][kk],      a1 = Xs[tm + 16][kk];
            float b0 = Ws[tn][kk],      b1 = Ws[tn + 16][kk];
            acc00 += a0 * b0; acc01 += a0 * b1;
            acc10 += a1 * b0; acc11 += a1 * b1;
        }
        __syncthreads();
    }
    float bb0 = bias[n0 + tn], bb1 = bias[n0 + tn + 16];
    acc00 += bb0; acc01 += bb1; acc10 += bb0; acc11 += bb1;
    if (relu) {
        acc00 = fmaxf(acc00, 0.f); acc01 = fmaxf(acc01, 0.f);
        acc10 = fmaxf(acc10, 0.f); acc11 = fmaxf(acc11, 0.f);
    }
    out[(size_t)(m0 + tm) * N + n0 + tn]           = acc00;
    out[(size_t)(m0 + tm) * N + n0 + tn + 16]      = acc01;
    out[(size_t)(m0 + tm + 16) * N + n0 + tn]      = acc10;
    out[(size_t)(m0 + tm + 16) * N + n0 + tn + 16] = acc11;
}

// One block per (b,h, 32-query tile). 256 threads: 8 lanes per query row.
__global__ __launch_bounds__(256) void k_attn(
    const float* __restrict__ q, const float* __restrict__ k,
    const float* __restrict__ v, float* __restrict__ o)
{
    __shared__ float Ks[NS][NDK + 1];
    __shared__ float Vs[NS][NDK + 1];
    __shared__ float Qs[32][NDK + 1];
    __shared__ float Ps[32][NS + 1];
    int t  = threadIdx.x;
    int bh = blockIdx.y;
    int b = bh >> 2, h = bh & 3;
    int qt = blockIdx.x * 32;
    int base = b * NS * ND + h * NDK;
    for (int idx = t; idx < NS * NDK; idx += 256) {
        int s = idx >> 5, d = idx & 31;
        Ks[s][d] = k[base + s * ND + d];
        Vs[s][d] = v[base + s * ND + d];
    }
    for (int idx = t; idx < 32 * NDK; idx += 256) {
        int s = idx >> 5, d = idx & 31;
        Qs[s][d] = q[base + (qt + s) * ND + d];
    }
    __syncthreads();
    int qi = t >> 3, kg = t & 7;
    const float scale = 0.17677669529663687f;  // 1/sqrt(32)
    for (int jj = 0; jj < 16; ++jj) {
        int j = kg * 16 + jj;
        float acc = 0.f;
        #pragma unroll
        for (int d = 0; d < NDK; ++d) acc += Qs[qi][d] * Ks[j][d];
        Ps[qi][j] = acc * scale;
    }
    // softmax over 128 keys; 8-lane group per row (groups never straddle waves)
    float mx = -1e30f;
    for (int jj = 0; jj < 16; ++jj) mx = fmaxf(mx, Ps[qi][kg * 16 + jj]);
    #pragma unroll
    for (int off = 1; off < 8; off <<= 1) mx = fmaxf(mx, __shfl_xor(mx, off));
    float sum = 0.f;
    for (int jj = 0; jj < 16; ++jj) {
        int j = kg * 16 + jj;
        float e = expf(Ps[qi][j] - mx);
        Ps[qi][j] = e;
        sum += e;
    }
    #pragma unroll
    for (int off = 1; off < 8; off <<= 1) sum += __shfl_xor(sum, off);
    float inv = 1.f / sum;
    for (int jj = 0; jj < 16; ++jj) Ps[qi][kg * 16 + jj] *= inv;
    __syncthreads();
    int d0 = (t & 7) * 4;
    float a0 = 0.f, a1 = 0.f, a2 = 0.f, a3 = 0.f;
    for (int j = 0; j < NS; ++j) {
        float p = Ps[qi][j];
        a0 += p * Vs[j][d0 + 0];
        a1 += p * Vs[j][d0 + 1];
        a2 += p * Vs[j][d0 + 2];
        a3 += p * Vs[j][d0 + 3];
    }
    int orow = base + (qt + qi) * ND + d0;
    o[orow + 0] = a0; o[orow + 1] = a1; o[orow + 2] = a2; o[orow + 3] = a3;
}

// x = LayerNorm(x + a) * g + be   (one block per row, 128 threads)
__global__ __launch_bounds__(128) void k_add_ln(
    float* __restrict__ x, const float* __restrict__ a,
    const float* __restrict__ g, const float* __restrict__ be)
{
    int row = blockIdx.x, t = threadIdx.x;
    int i = row * ND + t;
    float val = x[i] + a[i];
    float s = val, s2 = val * val;
    #pragma unroll
    for (int off = 1; off < 64; off <<= 1) {
        s  += __shfl_xor(s,  off);
        s2 += __shfl_xor(s2, off);
    }
    __shared__ float sh[4];
    if ((t & 63) == 0) { sh[t >> 6] = s; sh[2 + (t >> 6)] = s2; }
    __syncthreads();
    float ts = sh[0] + sh[1], ts2 = sh[2] + sh[3];
    float mu  = ts * (1.0f / ND);
    float var = ts2 * (1.0f / ND) - mu * mu;
    float r = 1.0f / sqrtf(var + 1e-5f);
    x[i] = (val - mu) * r * g[t] + be[t];
}

extern "C" void kernel_launch(void* const* d_in, const int* in_sizes, int n_in,
                              void* d_out, int out_size, void* d_ws, size_t ws_size,
                              hipStream_t stream)
{
    const int*   tok  = (const int*)d_in[0];
    const float* emb  = (const float*)d_in[1];
    const float* pos  = (const float*)d_in[2];
    const float* Wq   = (const float*)d_in[3];
    const float* bq   = (const float*)d_in[4];
    const float* Wk   = (const float*)d_in[5];
    const float* bk   = (const float*)d_in[6];
    const float* Wv   = (const float*)d_in[7];
    const float* bv   = (const float*)d_in[8];
    const float* Wo   = (const float*)d_in[9];
    const float* bo   = (const float*)d_in[10];
    const float* W1   = (const float*)d_in[11];
    const float* b1   = (const float*)d_in[12];
    const float* W2   = (const float*)d_in[13];
    const float* b2   = (const float*)d_in[14];
    const float* g1   = (const float*)d_in[15];
    const float* be1  = (const float*)d_in[16];
    const float* g2   = (const float*)d_in[17];
    const float* be2  = (const float*)d_in[18];
    const float* Wout = (const float*)d_in[19];
    const float* bout = (const float*)d_in[20];
    float* out = (float*)d_out;

    float* w     = (float*)d_ws;
    float* Wqf   = w;                   // 32768
    float* Wkf   = Wqf + 32768;
    float* Wvf   = Wkf + 32768;
    float* Wof   = Wvf + 32768;
    float* W1f   = Wof + 32768;         // 131072
    float* W2f   = W1f + 131072;        // 131072
    float* Woutf = W2f + 131072;        // 131072
    float* x     = Woutf + 131072;      // 32768
    float* qb    = x  + 32768;
    float* kb    = qb + 32768;
    float* vb    = kb + 32768;
    float* ab    = vb + 32768;
    float* pb    = ab + 32768;
    float* f1    = pb + 32768;          // 131072  (total ~3.25 MB)

    k_transform_all<<<2048, 256, 0, stream>>>(Wq, Wk, Wv, Wo, W1, W2, Wout, w);
    k_embed<<<128, 256, 0, stream>>>(tok, emb, pos, x);

    for (int l = 0; l < NL; ++l) {
        k_lmul_mm<<<dim3(4, 8), 256, 0, stream>>>(x,  Wqf + l * 16384, bq + l * 128, qb, 128, 128, 0);
        k_lmul_mm<<<dim3(4, 8), 256, 0, stream>>>(x,  Wkf + l * 16384, bk + l * 128, kb, 128, 128, 0);
        k_lmul_mm<<<dim3(4, 8), 256, 0, stream>>>(x,  Wvf + l * 16384, bv + l * 128, vb, 128, 128, 0);
        k_attn<<<dim3(4, 8), 256, 0, stream>>>(qb, kb, vb, ab);
        k_lmul_mm<<<dim3(4, 8), 256, 0, stream>>>(ab, Wof + l * 16384, bo + l * 128, pb, 128, 128, 0);
        k_add_ln<<<256, 128, 0, stream>>>(x, pb, g1 + l * 128, be1 + l * 128);
        k_lmul_mm<<<dim3(16, 8), 256, 0, stream>>>(x,  W1f + l * 65536, b1 + l * 512, f1, 512, 128, 1);
        k_lmul_mm<<<dim3(4, 8), 256, 0, stream>>>(f1, W2f + l * 65536, b2 + l * 128, pb, 128, 512, 0);
        k_add_ln<<<256, 128, 0, stream>>>(x, pb, g2 + l * 128, be2 + l * 128);
    }
    k_lmul_mm<<<dim3(32, 8), 256, 0, stream>>>(x, Woutf, bout, out, 1024, 128, 0);
}